// Round 1
// baseline (337.459 us; speedup 1.0000x reference)
//
#include <hip/hip_runtime.h>
#include <hip/hip_bf16.h>
#include <cstdint>

#define DIM   1024
#define HEADS 16
#define BB    32
#define NN    2048
#define DH    64

constexpr float SCALE = 0.03125f;  // 1/sqrt(1024)
constexpr float LN_EPS = 1e-5f;

// ---------------- helpers ----------------
__device__ __forceinline__ float block_sum256(float v, volatile float* red) {
  #pragma unroll
  for (int off = 32; off; off >>= 1) v += __shfl_xor(v, off);
  __syncthreads();
  if ((threadIdx.x & 63) == 0) red[threadIdx.x >> 6] = v;
  __syncthreads();
  return red[0] + red[1] + red[2] + red[3];
}

// ---------------- K1: Qp[d] = S . Wq[d,:] + bq[d] ----------------
__global__ void k_qp(const float* __restrict__ S, const float* __restrict__ Wq,
                     const float* __restrict__ bq, float* __restrict__ Qp) {
  int wave = threadIdx.x >> 6, lane = threadIdx.x & 63;
  int d0 = blockIdx.x * 16 + wave * 4;        // grid 64
  #pragma unroll
  for (int i = 0; i < 4; ++i) {
    int d = d0 + i;
    const float* wr = Wq + (size_t)d * DIM;
    float acc = 0.f;
    #pragma unroll
    for (int k = 0; k < 4; ++k) {
      int c = k * 256 + lane * 4;
      float4 a = *(const float4*)(wr + c);
      float4 s = *(const float4*)(S + c);
      acc += a.x * s.x + a.y * s.y + a.z * s.z + a.w * s.w;
    }
    #pragma unroll
    for (int off = 32; off; off >>= 1) acc += __shfl_xor(acc, off);
    if (lane == 0) Qp[d] = acc + bq[d];
  }
}

// ---------------- K2: qk[h,c] = sum_d Qp[h*64+d]*Wk[h*64+d,c]; qb[h] ----------------
__global__ void k_qk(const float* __restrict__ Qp, const float* __restrict__ Wk,
                     const float* __restrict__ bk, float* __restrict__ qk,
                     float* __restrict__ qb) {
  int i = blockIdx.x * 256 + threadIdx.x;     // grid 64 -> 16384
  int h = i >> 10, c = i & 1023;
  const float* qph = Qp + h * DH;
  float acc = 0.f;
  #pragma unroll 8
  for (int d = 0; d < DH; ++d) acc += qph[d] * Wk[(size_t)(h * DH + d) * DIM + c];
  qk[i] = acc;
  if (i < HEADS) {
    float a = 0.f;
    for (int d = 0; d < DH; ++d) a += Qp[i * DH + d] * bk[i * DH + d];
    qb[i] = a;
  }
}

// ---------------- K3: scores sc[row*16+h] = (X[row,:].qk[h,:] + qb[h])*SCALE ----------------
__global__ __launch_bounds__(256) void k_scores(const float* __restrict__ X,
                                                const float* __restrict__ qk,
                                                const float* __restrict__ qb,
                                                float* __restrict__ sc) {
  __shared__ float qkl[HEADS * DIM];          // 64 KB, XOR-swizzled on word bits 2-4
  for (int i = threadIdx.x; i < HEADS * DIM; i += 256) {
    int h = i >> 10, c = i & 1023;
    qkl[h * DIM + (c ^ ((h & 7) << 2))] = qk[i];
  }
  __syncthreads();
  int wave = threadIdx.x >> 6, lane = threadIdx.x & 63;
  int h = lane >> 2, j = lane & 3;
  int hx = (h & 7) << 2;
  const float* qrow = qkl + h * DIM;
  float qbh = qb[h];
  int base = blockIdx.x * 16 + wave * 4;      // grid 4096 -> 65536 rows
  const float* x0 = X + (size_t)base * DIM + j * 4;
  float a0 = 0.f, a1 = 0.f, a2 = 0.f, a3 = 0.f;
  #pragma unroll 4
  for (int t = 0; t < 64; ++t) {
    int cq = ((t << 4) | (j << 2)) ^ hx;      // swizzled, stays 16B-aligned
    float4 q  = *(const float4*)(qrow + cq);
    int c = t << 4;
    float4 xA = *(const float4*)(x0 + c);
    float4 xB = *(const float4*)(x0 + DIM + c);
    float4 xC = *(const float4*)(x0 + 2 * DIM + c);
    float4 xD = *(const float4*)(x0 + 3 * DIM + c);
    a0 += q.x * xA.x + q.y * xA.y + q.z * xA.z + q.w * xA.w;
    a1 += q.x * xB.x + q.y * xB.y + q.z * xB.z + q.w * xB.w;
    a2 += q.x * xC.x + q.y * xC.y + q.z * xC.z + q.w * xC.w;
    a3 += q.x * xD.x + q.y * xD.y + q.z * xD.z + q.w * xD.w;
  }
  a0 += __shfl_xor(a0, 1); a0 += __shfl_xor(a0, 2);
  a1 += __shfl_xor(a1, 1); a1 += __shfl_xor(a1, 2);
  a2 += __shfl_xor(a2, 1); a2 += __shfl_xor(a2, 2);
  a3 += __shfl_xor(a3, 1); a3 += __shfl_xor(a3, 2);
  if (j == 0) {
    sc[(size_t)(base + 0) * HEADS + h] = (a0 + qbh) * SCALE;
    sc[(size_t)(base + 1) * HEADS + h] = (a1 + qbh) * SCALE;
    sc[(size_t)(base + 2) * HEADS + h] = (a2 + qbh) * SCALE;
    sc[(size_t)(base + 3) * HEADS + h] = (a3 + qbh) * SCALE;
  }
}

// ---------------- K4: masked softmax over n, in place; lsum = sum(A) ----------------
__global__ void k_softmax(const int* __restrict__ mask, float* __restrict__ sc,
                          float* __restrict__ lsum) {
  int b = blockIdx.x >> 4, h = blockIdx.x & 15;   // grid 512
  int tid = threadIdx.x;
  const int* mb = mask + b * NN;
  float* sb = sc + (size_t)b * NN * HEADS + h;
  __shared__ float red[4];
  float mx = -3e38f;
  for (int n = tid; n < NN; n += 256)
    if (mb[n]) mx = fmaxf(mx, sb[(size_t)n * HEADS]);
  #pragma unroll
  for (int off = 32; off; off >>= 1) mx = fmaxf(mx, __shfl_xor(mx, off));
  if ((tid & 63) == 0) red[tid >> 6] = mx;
  __syncthreads();
  mx = fmaxf(fmaxf(red[0], red[1]), fmaxf(red[2], red[3]));
  float sum = 0.f;
  for (int n = tid; n < NN; n += 256) {
    float e = mb[n] ? __expf(sb[(size_t)n * HEADS] - mx) : 0.f;
    sb[(size_t)n * HEADS] = e;
    sum += e;
  }
  #pragma unroll
  for (int off = 32; off; off >>= 1) sum += __shfl_xor(sum, off);
  __syncthreads();
  if ((tid & 63) == 0) red[tid >> 6] = sum;
  __syncthreads();
  sum = red[0] + red[1] + red[2] + red[3];
  float inv = sum > 0.f ? 1.f / sum : 0.f;
  for (int n = tid; n < NN; n += 256) sb[(size_t)n * HEADS] *= inv;
  if (tid == 0) lsum[b * HEADS + h] = sum > 0.f ? 1.f : 0.f;
}

// ---------------- K5: Z partials: Zp[nchunk][b][h][c] = sum_{n in chunk} w*X ----------------
__global__ __launch_bounds__(256) void k_z(const float* __restrict__ X,
                                           const float* __restrict__ w,
                                           float* __restrict__ Zp) {
  int bid = blockIdx.x;                       // grid 512 = 32b x 4c x 4n
  int b = bid >> 4, cchunk = (bid >> 2) & 3, nchunk = bid & 3;
  int c = cchunk * 256 + threadIdx.x;
  const float* xb = X + ((size_t)b * NN + nchunk * 512) * DIM + c;
  const float* wb = w + ((size_t)b * NN + nchunk * 512) * HEADS;
  __shared__ float wl[128 * HEADS];           // 8 KB
  float acc[HEADS];
  #pragma unroll
  for (int h = 0; h < HEADS; ++h) acc[h] = 0.f;
  for (int tile = 0; tile < 512; tile += 128) {
    __syncthreads();
    for (int i = threadIdx.x; i < 128 * HEADS; i += 256) wl[i] = wb[tile * HEADS + i];
    __syncthreads();
    #pragma unroll 4
    for (int n = 0; n < 128; ++n) {
      float x = xb[(size_t)(tile + n) * DIM];
      const float* wn = wl + n * HEADS;       // broadcast read
      #pragma unroll
      for (int h = 0; h < HEADS; ++h) acc[h] += wn[h] * x;
    }
  }
  float* zp = Zp + ((size_t)(nchunk * BB + b)) * HEADS * DIM + c;
  #pragma unroll
  for (int h = 0; h < HEADS; ++h) zp[(size_t)h * DIM] = acc[h];
}

// ---------------- K5b: reduce partials ----------------
__global__ void k_zred(const float* __restrict__ Zp, float* __restrict__ Z) {
  int i = blockIdx.x * 256 + threadIdx.x;     // grid 2048 -> 524288
  const int STRIDE = BB * HEADS * DIM;
  Z[i] = Zp[i] + Zp[STRIDE + i] + Zp[2 * STRIDE + i] + Zp[3 * STRIDE + i];
}

// ---------------- K6: T[b,df] = Z[b,h(df),:] . Wv[df,:] ----------------
__global__ void k_ov(const float* __restrict__ Z, const float* __restrict__ Wv,
                     float* __restrict__ T) {
  int wave = threadIdx.x >> 6, lane = threadIdx.x & 63;
  int dfb = blockIdx.x;                       // grid 256
  for (int dot = wave; dot < 128; dot += 4) {
    int b = dot >> 2, dfl = dot & 3;
    int df = dfb * 4 + dfl, h = df >> 6;
    const float* wr = Wv + (size_t)df * DIM + lane * 4;
    const float* zr = Z + ((size_t)b * HEADS + h) * DIM + lane * 4;
    float acc = 0.f;
    #pragma unroll
    for (int k = 0; k < 4; ++k) {
      float4 a = *(const float4*)(wr + k * 256);
      float4 z = *(const float4*)(zr + k * 256);
      acc += a.x * z.x + a.y * z.y + a.z * z.z + a.w * z.w;
    }
    #pragma unroll
    for (int off = 32; off; off >>= 1) acc += __shfl_xor(acc, off);
    if (lane == 0) T[(size_t)b * DIM + df] = acc;
  }
}

// ---------------- K7: U = LN0(S + T + l*bv) ----------------
__global__ void k_ln0(const float* __restrict__ S, const float* __restrict__ T,
                      const float* __restrict__ lsum, const float* __restrict__ bv,
                      const float* __restrict__ g0, const float* __restrict__ b0,
                      float* __restrict__ U) {
  __shared__ float red[4];
  int b = blockIdx.x, tid = threadIdx.x, d0 = tid * 4;   // grid 32
  float4 s4 = *(const float4*)(S + d0);
  float4 t4 = *(const float4*)(T + (size_t)b * DIM + d0);
  float4 v4 = *(const float4*)(bv + d0);
  float lh = lsum[b * HEADS + (d0 >> 6)];
  float x0 = s4.x + t4.x + lh * v4.x;
  float x1 = s4.y + t4.y + lh * v4.y;
  float x2 = s4.z + t4.z + lh * v4.z;
  float x3 = s4.w + t4.w + lh * v4.w;
  float mu = block_sum256(x0 + x1 + x2 + x3, red) * (1.f / DIM);
  float e0 = x0 - mu, e1 = x1 - mu, e2 = x2 - mu, e3 = x3 - mu;
  float var = block_sum256(e0 * e0 + e1 * e1 + e2 * e2 + e3 * e3, red) * (1.f / DIM);
  float r = rsqrtf(var + LN_EPS);
  float4 g4 = *(const float4*)(g0 + d0);
  float4 bb4 = *(const float4*)(b0 + d0);
  float4 o;
  o.x = e0 * r * g4.x + bb4.x;
  o.y = e1 * r * g4.y + bb4.y;
  o.z = e2 * r * g4.z + bb4.z;
  o.w = e3 * r * g4.w + bb4.w;
  *(float4*)(U + (size_t)b * DIM + d0) = o;
}

// ---------------- K8: R = relu(U . Wo^T + bo) ----------------
__global__ void k_wo(const float* __restrict__ U, const float* __restrict__ Wo,
                     const float* __restrict__ bo, float* __restrict__ R) {
  int wave = threadIdx.x >> 6, lane = threadIdx.x & 63;
  int dfb = blockIdx.x;                       // grid 256
  for (int dot = wave; dot < 128; dot += 4) {
    int b = dot >> 2, dfl = dot & 3;
    int df = dfb * 4 + dfl;
    const float* wr = Wo + (size_t)df * DIM + lane * 4;
    const float* ur = U + (size_t)b * DIM + lane * 4;
    float acc = 0.f;
    #pragma unroll
    for (int k = 0; k < 4; ++k) {
      float4 a = *(const float4*)(wr + k * 256);
      float4 u = *(const float4*)(ur + k * 256);
      acc += a.x * u.x + a.y * u.y + a.z * u.z + a.w * u.w;
    }
    #pragma unroll
    for (int off = 32; off; off >>= 1) acc += __shfl_xor(acc, off);
    if (lane == 0) R[(size_t)b * DIM + df] = fmaxf(acc + bo[df], 0.f);
  }
}

// ---------------- K9: out = LN1(U + R) ----------------
__global__ void k_ln1(const float* __restrict__ U, const float* __restrict__ R,
                      const float* __restrict__ g1, const float* __restrict__ b1,
                      float* __restrict__ out) {
  __shared__ float red[4];
  int b = blockIdx.x, tid = threadIdx.x, d0 = tid * 4;   // grid 32
  float4 u4 = *(const float4*)(U + (size_t)b * DIM + d0);
  float4 r4 = *(const float4*)(R + (size_t)b * DIM + d0);
  float x0 = u4.x + r4.x, x1 = u4.y + r4.y, x2 = u4.z + r4.z, x3 = u4.w + r4.w;
  float mu = block_sum256(x0 + x1 + x2 + x3, red) * (1.f / DIM);
  float e0 = x0 - mu, e1 = x1 - mu, e2 = x2 - mu, e3 = x3 - mu;
  float var = block_sum256(e0 * e0 + e1 * e1 + e2 * e2 + e3 * e3, red) * (1.f / DIM);
  float r = rsqrtf(var + LN_EPS);
  float4 g4 = *(const float4*)(g1 + d0);
  float4 bb4 = *(const float4*)(b1 + d0);
  float4 o;
  o.x = e0 * r * g4.x + bb4.x;
  o.y = e1 * r * g4.y + bb4.y;
  o.z = e2 * r * g4.z + bb4.z;
  o.w = e3 * r * g4.w + bb4.w;
  *(float4*)(out + (size_t)b * DIM + d0) = o;
}

extern "C" void kernel_launch(void* const* d_in, const int* in_sizes, int n_in,
                              void* d_out, int out_size, void* d_ws, size_t ws_size,
                              hipStream_t stream) {
  (void)in_sizes; (void)n_in; (void)out_size; (void)ws_size;
  const float* X  = (const float*)d_in[0];
  const int*   mask = (const int*)d_in[1];
  const float* S  = (const float*)d_in[2];
  const float* Wq = (const float*)d_in[3];
  const float* bq = (const float*)d_in[4];
  const float* Wk = (const float*)d_in[5];
  const float* bk = (const float*)d_in[6];
  const float* Wv = (const float*)d_in[7];
  const float* bv = (const float*)d_in[8];
  const float* Wo = (const float*)d_in[9];
  const float* bo = (const float*)d_in[10];
  const float* g0 = (const float*)d_in[11];
  const float* b0 = (const float*)d_in[12];
  const float* g1 = (const float*)d_in[13];
  const float* b1 = (const float*)d_in[14];
  float* out = (float*)d_out;

  float* W    = (float*)d_ws;
  float* sc   = W;                            // 1,048,576 f (scores -> weights, in place)
  float* Zp   = W + 1048576;                  // 2,097,152 f (4 n-chunk partials)
  float* Z    = W + 3145728;                  //   524,288 f
  float* Qp   = W + 3670016;                  //     1,024 f
  float* qk   = W + 3671040;                  //    16,384 f
  float* qb   = W + 3687424;                  //        16 f
  float* lsum = W + 3687440;                  //       512 f
  float* T    = sc;                           // alias: sc dead after k_z
  float* U    = sc + 32768;
  float* R    = sc + 65536;

  k_qp     <<<64,   256, 0, stream>>>(S, Wq, bq, Qp);
  k_qk     <<<64,   256, 0, stream>>>(Qp, Wk, bk, qk, qb);
  k_scores <<<4096, 256, 0, stream>>>(X, qk, qb, sc);
  k_softmax<<<512,  256, 0, stream>>>(mask, sc, lsum);
  k_z      <<<512,  256, 0, stream>>>(X, sc, Zp);
  k_zred   <<<2048, 256, 0, stream>>>(Zp, Z);
  k_ov     <<<256,  256, 0, stream>>>(Z, Wv, T);
  k_ln0    <<<32,   256, 0, stream>>>(S, T, lsum, bv, g0, b0, U);
  k_wo     <<<256,  256, 0, stream>>>(U, Wo, bo, R);
  k_ln1    <<<32,   256, 0, stream>>>(U, R, g1, b1, out);
}

// Round 2
// 305.010 us; speedup vs baseline: 1.1064x; 1.1064x over previous
//
#include <hip/hip_runtime.h>
#include <hip/hip_bf16.h>
#include <cstdint>

#define DIM   1024
#define HEADS 16
#define BB    32
#define NN    2048
#define DH    64

constexpr float SCALE = 0.03125f;  // 1/sqrt(1024)
constexpr float LN_EPS = 1e-5f;

// ---------------- helpers ----------------
__device__ __forceinline__ float block_sum256(float v, volatile float* red) {
  #pragma unroll
  for (int off = 32; off; off >>= 1) v += __shfl_xor(v, off);
  __syncthreads();
  if ((threadIdx.x & 63) == 0) red[threadIdx.x >> 6] = v;
  __syncthreads();
  return red[0] + red[1] + red[2] + red[3];
}

// ---------------- K1: Qp[d] = S . Wq[d,:] + bq[d] ----------------
__global__ void k_qp(const float* __restrict__ S, const float* __restrict__ Wq,
                     const float* __restrict__ bq, float* __restrict__ Qp) {
  int wave = threadIdx.x >> 6, lane = threadIdx.x & 63;
  int d0 = blockIdx.x * 16 + wave * 4;        // grid 64
  #pragma unroll
  for (int i = 0; i < 4; ++i) {
    int d = d0 + i;
    const float* wr = Wq + (size_t)d * DIM;
    float acc = 0.f;
    #pragma unroll
    for (int k = 0; k < 4; ++k) {
      int c = k * 256 + lane * 4;
      float4 a = *(const float4*)(wr + c);
      float4 s = *(const float4*)(S + c);
      acc += a.x * s.x + a.y * s.y + a.z * s.z + a.w * s.w;
    }
    #pragma unroll
    for (int off = 32; off; off >>= 1) acc += __shfl_xor(acc, off);
    if (lane == 0) Qp[d] = acc + bq[d];
  }
}

// ---------------- K2: qk[h,c] = sum_d Qp[h*64+d]*Wk[h*64+d,c]; qb[h] ----------------
__global__ void k_qk(const float* __restrict__ Qp, const float* __restrict__ Wk,
                     const float* __restrict__ bk, float* __restrict__ qk,
                     float* __restrict__ qb) {
  int i = blockIdx.x * 256 + threadIdx.x;     // grid 64 -> 16384
  int h = i >> 10, c = i & 1023;
  const float* qph = Qp + h * DH;
  float acc = 0.f;
  #pragma unroll 8
  for (int d = 0; d < DH; ++d) acc += qph[d] * Wk[(size_t)(h * DH + d) * DIM + c];
  qk[i] = acc;
  if (i < HEADS) {
    float a = 0.f;
    for (int d = 0; d < DH; ++d) a += Qp[i * DH + d] * bk[i * DH + d];
    qb[i] = a;
  }
}

// ---------------- K3 v2: partial scores, K split in halves ----------------
// grid 2048 = rowblk(1024) x half(2); P[half][row][h] (no bias/scale yet)
__global__ __launch_bounds__(256) void k_scores2(const float* __restrict__ X,
                                                 const float* __restrict__ qk,
                                                 float* __restrict__ P) {
  int half = blockIdx.x & 1;
  int rowblk = blockIdx.x >> 1;
  __shared__ float4 qkl[HEADS * 128];         // 32 KB: qk[h][half*512 + 4q .. 4q+3]
  for (int i = threadIdx.x; i < HEADS * 128; i += 256) {
    int h = i >> 7, q = i & 127;
    qkl[i] = *(const float4*)(qk + (size_t)h * DIM + half * 512 + q * 4);
  }
  __syncthreads();
  int r = threadIdx.x >> 2;                   // 0..63  (row within block)
  int j = threadIdx.x & 3;                    // c-quarter interleave
  size_t row = (size_t)rowblk * 64 + r;
  const float* xrow = X + row * DIM + half * 512;
  float acc[HEADS];
  #pragma unroll
  for (int h = 0; h < HEADS; ++h) acc[h] = 0.f;
  #pragma unroll 8
  for (int cc = 0; cc < 32; ++cc) {
    int q = cc * 4 + j;                       // float4 index within the half
    float4 x4 = *(const float4*)(xrow + q * 4);
    #pragma unroll
    for (int h = 0; h < HEADS; ++h) {
      float4 q4 = qkl[h * 128 + q];           // 4 unique addrs/wave -> broadcast
      acc[h] += x4.x * q4.x + x4.y * q4.y + x4.z * q4.z + x4.w * q4.w;
    }
  }
  #pragma unroll
  for (int h = 0; h < HEADS; ++h) {
    acc[h] += __shfl_xor(acc[h], 1);
    acc[h] += __shfl_xor(acc[h], 2);
  }
  if (j == 0) {
    float4* d4 = (float4*)(P + ((size_t)half * 65536 + row) * HEADS);
    d4[0] = make_float4(acc[0],  acc[1],  acc[2],  acc[3]);
    d4[1] = make_float4(acc[4],  acc[5],  acc[6],  acc[7]);
    d4[2] = make_float4(acc[8],  acc[9],  acc[10], acc[11]);
    d4[3] = make_float4(acc[12], acc[13], acc[14], acc[15]);
  }
}

// ---------------- K4 v2: combine halves + bias + scale + masked softmax ----------------
// writes weights w in [b][h][n] layout (contiguous per block)
__global__ void k_softmax2(const int* __restrict__ mask, const float* __restrict__ P,
                           const float* __restrict__ qb, float* __restrict__ w,
                           float* __restrict__ lsum) {
  int b = blockIdx.x >> 4, h = blockIdx.x & 15;   // grid 512
  int tid = threadIdx.x;
  const int* mb = mask + b * NN;
  const float* p0 = P + ((size_t)b * NN) * HEADS + h;
  const float* p1 = p0 + (size_t)65536 * HEADS;
  float qbh = qb[h];
  __shared__ float red[4];
  float s[8]; int m[8];
  float mx = -3e38f;
  #pragma unroll
  for (int i = 0; i < 8; ++i) {
    int n = tid + i * 256;
    m[i] = mb[n];
    s[i] = (p0[(size_t)n * HEADS] + p1[(size_t)n * HEADS] + qbh) * SCALE;
    if (m[i]) mx = fmaxf(mx, s[i]);
  }
  #pragma unroll
  for (int off = 32; off; off >>= 1) mx = fmaxf(mx, __shfl_xor(mx, off));
  if ((tid & 63) == 0) red[tid >> 6] = mx;
  __syncthreads();
  mx = fmaxf(fmaxf(red[0], red[1]), fmaxf(red[2], red[3]));
  float sum = 0.f;
  #pragma unroll
  for (int i = 0; i < 8; ++i) {
    float e = m[i] ? __expf(s[i] - mx) : 0.f;
    s[i] = e;
    sum += e;
  }
  #pragma unroll
  for (int off = 32; off; off >>= 1) sum += __shfl_xor(sum, off);
  __syncthreads();
  if ((tid & 63) == 0) red[tid >> 6] = sum;
  __syncthreads();
  sum = red[0] + red[1] + red[2] + red[3];
  float inv = sum > 0.f ? 1.f / sum : 0.f;
  float* wb = w + ((size_t)b * HEADS + h) * NN;
  #pragma unroll
  for (int i = 0; i < 8; ++i) wb[tid + i * 256] = s[i] * inv;
  if (tid == 0) lsum[b * HEADS + h] = sum > 0.f ? 1.f : 0.f;
}

// ---------------- K5: Z partials (w now [b][h][n]) ----------------
__global__ __launch_bounds__(256) void k_z(const float* __restrict__ X,
                                           const float* __restrict__ w,
                                           float* __restrict__ Zp) {
  int bid = blockIdx.x;                       // grid 512 = 32b x 4c x 4n
  int b = bid >> 4, cchunk = (bid >> 2) & 3, nchunk = bid & 3;
  int c = cchunk * 256 + threadIdx.x;
  const float* xb = X + ((size_t)b * NN + nchunk * 512) * DIM + c;
  const float* wb = w + ((size_t)b * HEADS) * NN + nchunk * 512;
  __shared__ float wl[HEADS * 128];           // 8 KB, [h][n]
  float acc[HEADS];
  #pragma unroll
  for (int h = 0; h < HEADS; ++h) acc[h] = 0.f;
  for (int tile = 0; tile < 512; tile += 128) {
    __syncthreads();
    for (int i = threadIdx.x; i < HEADS * 128; i += 256)
      wl[i] = wb[(size_t)(i >> 7) * NN + tile + (i & 127)];
    __syncthreads();
    #pragma unroll 4
    for (int n = 0; n < 128; ++n) {
      float x = xb[(size_t)(tile + n) * DIM];
      #pragma unroll
      for (int h = 0; h < HEADS; ++h) acc[h] += wl[h * 128 + n] * x;  // broadcast
    }
  }
  float* zp = Zp + ((size_t)(nchunk * BB + b)) * HEADS * DIM + c;
  #pragma unroll
  for (int h = 0; h < HEADS; ++h) zp[(size_t)h * DIM] = acc[h];
}

// ---------------- K5b: reduce partials ----------------
__global__ void k_zred(const float* __restrict__ Zp, float* __restrict__ Z) {
  int i = blockIdx.x * 256 + threadIdx.x;     // grid 2048 -> 524288
  const int STRIDE = BB * HEADS * DIM;
  Z[i] = Zp[i] + Zp[STRIDE + i] + Zp[2 * STRIDE + i] + Zp[3 * STRIDE + i];
}

// ---------------- K6: T[b,df] = Z[b,h(df),:] . Wv[df,:] ----------------
__global__ void k_ov(const float* __restrict__ Z, const float* __restrict__ Wv,
                     float* __restrict__ T) {
  int wave = threadIdx.x >> 6, lane = threadIdx.x & 63;
  int dfb = blockIdx.x;                       // grid 256
  for (int dot = wave; dot < 128; dot += 4) {
    int b = dot >> 2, dfl = dot & 3;
    int df = dfb * 4 + dfl, h = df >> 6;
    const float* wr = Wv + (size_t)df * DIM + lane * 4;
    const float* zr = Z + ((size_t)b * HEADS + h) * DIM + lane * 4;
    float acc = 0.f;
    #pragma unroll
    for (int k = 0; k < 4; ++k) {
      float4 a = *(const float4*)(wr + k * 256);
      float4 z = *(const float4*)(zr + k * 256);
      acc += a.x * z.x + a.y * z.y + a.z * z.z + a.w * z.w;
    }
    #pragma unroll
    for (int off = 32; off; off >>= 1) acc += __shfl_xor(acc, off);
    if (lane == 0) T[(size_t)b * DIM + df] = acc;
  }
}

// ---------------- K7: U = LN0(S + T + l*bv) ----------------
__global__ void k_ln0(const float* __restrict__ S, const float* __restrict__ T,
                      const float* __restrict__ lsum, const float* __restrict__ bv,
                      const float* __restrict__ g0, const float* __restrict__ b0,
                      float* __restrict__ U) {
  __shared__ float red[4];
  int b = blockIdx.x, tid = threadIdx.x, d0 = tid * 4;   // grid 32
  float4 s4 = *(const float4*)(S + d0);
  float4 t4 = *(const float4*)(T + (size_t)b * DIM + d0);
  float4 v4 = *(const float4*)(bv + d0);
  float lh = lsum[b * HEADS + (d0 >> 6)];
  float x0 = s4.x + t4.x + lh * v4.x;
  float x1 = s4.y + t4.y + lh * v4.y;
  float x2 = s4.z + t4.z + lh * v4.z;
  float x3 = s4.w + t4.w + lh * v4.w;
  float mu = block_sum256(x0 + x1 + x2 + x3, red) * (1.f / DIM);
  float e0 = x0 - mu, e1 = x1 - mu, e2 = x2 - mu, e3 = x3 - mu;
  float var = block_sum256(e0 * e0 + e1 * e1 + e2 * e2 + e3 * e3, red) * (1.f / DIM);
  float r = rsqrtf(var + LN_EPS);
  float4 g4 = *(const float4*)(g0 + d0);
  float4 bb4 = *(const float4*)(b0 + d0);
  float4 o;
  o.x = e0 * r * g4.x + bb4.x;
  o.y = e1 * r * g4.y + bb4.y;
  o.z = e2 * r * g4.z + bb4.z;
  o.w = e3 * r * g4.w + bb4.w;
  *(float4*)(U + (size_t)b * DIM + d0) = o;
}

// ---------------- K8: R = relu(U . Wo^T + bo) ----------------
__global__ void k_wo(const float* __restrict__ U, const float* __restrict__ Wo,
                     const float* __restrict__ bo, float* __restrict__ R) {
  int wave = threadIdx.x >> 6, lane = threadIdx.x & 63;
  int dfb = blockIdx.x;                       // grid 256
  for (int dot = wave; dot < 128; dot += 4) {
    int b = dot >> 2, dfl = dot & 3;
    int df = dfb * 4 + dfl;
    const float* wr = Wo + (size_t)df * DIM + lane * 4;
    const float* ur = U + (size_t)b * DIM + lane * 4;
    float acc = 0.f;
    #pragma unroll
    for (int k = 0; k < 4; ++k) {
      float4 a = *(const float4*)(wr + k * 256);
      float4 u = *(const float4*)(ur + k * 256);
      acc += a.x * u.x + a.y * u.y + a.z * u.z + a.w * u.w;
    }
    #pragma unroll
    for (int off = 32; off; off >>= 1) acc += __shfl_xor(acc, off);
    if (lane == 0) R[(size_t)b * DIM + df] = fmaxf(acc + bo[df], 0.f);
  }
}

// ---------------- K9: out = LN1(U + R) ----------------
__global__ void k_ln1(const float* __restrict__ U, const float* __restrict__ R,
                      const float* __restrict__ g1, const float* __restrict__ b1,
                      float* __restrict__ out) {
  __shared__ float red[4];
  int b = blockIdx.x, tid = threadIdx.x, d0 = tid * 4;   // grid 32
  float4 u4 = *(const float4*)(U + (size_t)b * DIM + d0);
  float4 r4 = *(const float4*)(R + (size_t)b * DIM + d0);
  float x0 = u4.x + r4.x, x1 = u4.y + r4.y, x2 = u4.z + r4.z, x3 = u4.w + r4.w;
  float mu = block_sum256(x0 + x1 + x2 + x3, red) * (1.f / DIM);
  float e0 = x0 - mu, e1 = x1 - mu, e2 = x2 - mu, e3 = x3 - mu;
  float var = block_sum256(e0 * e0 + e1 * e1 + e2 * e2 + e3 * e3, red) * (1.f / DIM);
  float r = rsqrtf(var + LN_EPS);
  float4 g4 = *(const float4*)(g1 + d0);
  float4 bb4 = *(const float4*)(b1 + d0);
  float4 o;
  o.x = e0 * r * g4.x + bb4.x;
  o.y = e1 * r * g4.y + bb4.y;
  o.z = e2 * r * g4.z + bb4.z;
  o.w = e3 * r * g4.w + bb4.w;
  *(float4*)(out + (size_t)b * DIM + d0) = o;
}

extern "C" void kernel_launch(void* const* d_in, const int* in_sizes, int n_in,
                              void* d_out, int out_size, void* d_ws, size_t ws_size,
                              hipStream_t stream) {
  (void)in_sizes; (void)n_in; (void)out_size; (void)ws_size;
  const float* X  = (const float*)d_in[0];
  const int*   mask = (const int*)d_in[1];
  const float* S  = (const float*)d_in[2];
  const float* Wq = (const float*)d_in[3];
  const float* bq = (const float*)d_in[4];
  const float* Wk = (const float*)d_in[5];
  const float* bk = (const float*)d_in[6];
  const float* Wv = (const float*)d_in[7];
  const float* bv = (const float*)d_in[8];
  const float* Wo = (const float*)d_in[9];
  const float* bo = (const float*)d_in[10];
  const float* g0 = (const float*)d_in[11];
  const float* b0 = (const float*)d_in[12];
  const float* g1 = (const float*)d_in[13];
  const float* b1 = (const float*)d_in[14];
  float* out = (float*)d_out;

  float* W    = (float*)d_ws;
  float* P    = W;                 // 2,097,152 f  (score partials, 2 halves)
  float* Zp   = W;                 // alias: P dead after k_softmax2
  float* w    = W + 2097152;       // 1,048,576 f  (attention weights [b][h][n])
  float* Z    = W + 3145728;       //   524,288 f
  float* Qp   = W + 3670016;       //     1,024 f
  float* qk   = W + 3671040;       //    16,384 f
  float* qb   = W + 3687424;       //        16 f
  float* lsum = W + 3687440;       //       512 f
  float* T    = w;                 // alias: w dead after k_z
  float* U    = w + 32768;
  float* R    = w + 65536;

  k_qp      <<<64,   256, 0, stream>>>(S, Wq, bq, Qp);
  k_qk      <<<64,   256, 0, stream>>>(Qp, Wk, bk, qk, qb);
  k_scores2 <<<2048, 256, 0, stream>>>(X, qk, P);
  k_softmax2<<<512,  256, 0, stream>>>(mask, P, qb, w, lsum);
  k_z       <<<512,  256, 0, stream>>>(X, w, Zp);
  k_zred    <<<2048, 256, 0, stream>>>(Zp, Z);
  k_ov      <<<256,  256, 0, stream>>>(Z, Wv, T);
  k_ln0     <<<32,   256, 0, stream>>>(S, T, lsum, bv, g0, b0, U);
  k_wo      <<<256,  256, 0, stream>>>(U, Wo, bo, R);
  k_ln1     <<<32,   256, 0, stream>>>(U, R, g1, b1, out);
}

// Round 3
// 197.927 us; speedup vs baseline: 1.7050x; 1.5410x over previous
//
#include <hip/hip_runtime.h>
#include <hip/hip_bf16.h>
#include <cstdint>

#define DIM   1024
#define HEADS 16
#define BB    32
#define NN    2048
#define DH    64

constexpr float SCALE = 0.03125f;  // 1/sqrt(1024)
constexpr float LN_EPS = 1e-5f;

typedef __attribute__((ext_vector_type(8))) short short8v;
typedef __attribute__((ext_vector_type(4))) float f32x4;

__device__ __forceinline__ short f2bf(float f) {
  union { __hip_bfloat16 h; short s; } u;
  u.h = __float2bfloat16(f);
  return u.s;
}
__device__ __forceinline__ short8v pack8(float4 a, float4 b) {
  short8v v;
  v[0] = f2bf(a.x); v[1] = f2bf(a.y); v[2] = f2bf(a.z); v[3] = f2bf(a.w);
  v[4] = f2bf(b.x); v[5] = f2bf(b.y); v[6] = f2bf(b.z); v[7] = f2bf(b.w);
  return v;
}
__device__ __forceinline__ void fma4(float4& a, float s, float4 x) {
  a.x += s * x.x; a.y += s * x.y; a.z += s * x.z; a.w += s * x.w;
}

// ---------------- helpers ----------------
__device__ __forceinline__ float block_sum256(float v, volatile float* red) {
  #pragma unroll
  for (int off = 32; off; off >>= 1) v += __shfl_xor(v, off);
  __syncthreads();
  if ((threadIdx.x & 63) == 0) red[threadIdx.x >> 6] = v;
  __syncthreads();
  return red[0] + red[1] + red[2] + red[3];
}

// ---------------- K1: Qp[d] = S . Wq[d,:] + bq[d] ----------------
__global__ void k_qp(const float* __restrict__ S, const float* __restrict__ Wq,
                     const float* __restrict__ bq, float* __restrict__ Qp) {
  int wave = threadIdx.x >> 6, lane = threadIdx.x & 63;
  int d0 = blockIdx.x * 16 + wave * 4;        // grid 64
  #pragma unroll
  for (int i = 0; i < 4; ++i) {
    int d = d0 + i;
    const float* wr = Wq + (size_t)d * DIM;
    float acc = 0.f;
    #pragma unroll
    for (int k = 0; k < 4; ++k) {
      int c = k * 256 + lane * 4;
      float4 a = *(const float4*)(wr + c);
      float4 s = *(const float4*)(S + c);
      acc += a.x * s.x + a.y * s.y + a.z * s.z + a.w * s.w;
    }
    #pragma unroll
    for (int off = 32; off; off >>= 1) acc += __shfl_xor(acc, off);
    if (lane == 0) Qp[d] = acc + bq[d];
  }
}

// ---------------- K2: qk[h,c] = sum_d Qp[h*64+d]*Wk[h*64+d,c]; qb[h] ----------------
__global__ void k_qk(const float* __restrict__ Qp, const float* __restrict__ Wk,
                     const float* __restrict__ bk, float* __restrict__ qk,
                     float* __restrict__ qb) {
  int i = blockIdx.x * 256 + threadIdx.x;     // grid 64 -> 16384
  int h = i >> 10, c = i & 1023;
  const float* qph = Qp + h * DH;
  float acc = 0.f;
  #pragma unroll 8
  for (int d = 0; d < DH; ++d) acc += qph[d] * Wk[(size_t)(h * DH + d) * DIM + c];
  qk[i] = acc;
  if (i < HEADS) {
    float a = 0.f;
    for (int d = 0; d < DH; ++d) a += Qp[i * DH + d] * bk[i * DH + d];
    qb[i] = a;
  }
}

// ---------------- K3 v3: MFMA scores. P[row][h] = X[row,:] . qk[h,:] ----------------
// grid 512, 256 thr; wave computes 2 M-tiles of 16 rows; B (qk) staged bf16 in LDS.
__global__ __launch_bounds__(256) void k_scores3(const float* __restrict__ X,
                                                 const float* __restrict__ qk,
                                                 float* __restrict__ P) {
  __shared__ short qlds[HEADS * 1024];        // 32 KB bf16, 8-elem slots, XOR swizzle
  int tid = threadIdx.x;
  for (int i = tid; i < HEADS * 128; i += 256) {
    int h = i >> 7, slot = i & 127;
    const float4* qg = (const float4*)(qk + (size_t)h * DIM) + slot * 2;
    float4 f0 = qg[0], f1 = qg[1];
    int ds = slot ^ (h & 7);
    *(short8v*)(qlds + h * 1024 + ds * 8) = pack8(f0, f1);
  }
  __syncthreads();
  int wv = tid >> 6, lane = tid & 63;
  int r16 = lane & 15, kg = lane >> 4;
  size_t rowbase = ((size_t)blockIdx.x * 4 + wv) * 32;
  const float* x0 = X + (rowbase + r16) * DIM + kg * 8;
  const float* x1 = x0 + (size_t)16 * DIM;
  const short* qrow = qlds + r16 * 1024;
  int hx = r16 & 7;
  f32x4 acc0 = {0.f, 0.f, 0.f, 0.f}, acc1 = {0.f, 0.f, 0.f, 0.f};
  #pragma unroll 4
  for (int k0 = 0; k0 < DIM; k0 += 32) {
    float4 a00 = *(const float4*)(x0 + k0);
    float4 a01 = *(const float4*)(x0 + k0 + 4);
    float4 a10 = *(const float4*)(x1 + k0);
    float4 a11 = *(const float4*)(x1 + k0 + 4);
    short8v bfr = *(const short8v*)(qrow + ((((k0 >> 3) + kg) ^ hx) << 3));
    short8v af0 = pack8(a00, a01);
    short8v af1 = pack8(a10, a11);
    acc0 = __builtin_amdgcn_mfma_f32_16x16x32_bf16(af0, bfr, acc0, 0, 0, 0);
    acc1 = __builtin_amdgcn_mfma_f32_16x16x32_bf16(af1, bfr, acc1, 0, 0, 0);
  }
  // C/D: col = lane&15 (=h), row = kg*4 + j
  float* p0 = P + (rowbase + kg * 4) * HEADS + r16;
  #pragma unroll
  for (int j = 0; j < 4; ++j) p0[j * HEADS] = acc0[j];
  float* p1 = p0 + 16 * HEADS;
  #pragma unroll
  for (int j = 0; j < 4; ++j) p1[j * HEADS] = acc1[j];
}

// ---------------- K4: bias + scale + masked softmax; w out as [b][n][h] ----------------
__global__ void k_softmax2(const int* __restrict__ mask, const float* __restrict__ P,
                           const float* __restrict__ qb, float* __restrict__ w,
                           float* __restrict__ lsum) {
  int b = blockIdx.x >> 4, h = blockIdx.x & 15;   // grid 512
  int tid = threadIdx.x;
  const int* mb = mask + b * NN;
  const float* p0 = P + ((size_t)b * NN) * HEADS + h;
  float qbh = qb[h];
  __shared__ float red[4];
  float s[8]; int m[8];
  float mx = -3e38f;
  #pragma unroll
  for (int i = 0; i < 8; ++i) {
    int n = tid + i * 256;
    m[i] = mb[n];
    s[i] = (p0[(size_t)n * HEADS] + qbh) * SCALE;
    if (m[i]) mx = fmaxf(mx, s[i]);
  }
  #pragma unroll
  for (int off = 32; off; off >>= 1) mx = fmaxf(mx, __shfl_xor(mx, off));
  if ((tid & 63) == 0) red[tid >> 6] = mx;
  __syncthreads();
  mx = fmaxf(fmaxf(red[0], red[1]), fmaxf(red[2], red[3]));
  float sum = 0.f;
  #pragma unroll
  for (int i = 0; i < 8; ++i) {
    float e = m[i] ? __expf(s[i] - mx) : 0.f;
    s[i] = e;
    sum += e;
  }
  #pragma unroll
  for (int off = 32; off; off >>= 1) sum += __shfl_xor(sum, off);
  __syncthreads();
  if ((tid & 63) == 0) red[tid >> 6] = sum;
  __syncthreads();
  sum = red[0] + red[1] + red[2] + red[3];
  float inv = sum > 0.f ? 1.f / sum : 0.f;
  float* wb = w + (size_t)b * NN * HEADS + h;
  #pragma unroll
  for (int i = 0; i < 8; ++i) wb[(size_t)(tid + i * 256) * HEADS] = s[i] * inv;
  if (tid == 0) lsum[b * HEADS + h] = sum > 0.f ? 1.f : 0.f;
}

// ---------------- K5 v2: Z partials; w[n][0..15] is wave-uniform (scalar loads) ----------------
__global__ __launch_bounds__(256) void k_z2(const float* __restrict__ X,
                                            const float* __restrict__ w,
                                            float* __restrict__ Zp,
                                            int nchunk, int NC) {
  int nc = blockIdx.x % nchunk;
  int b  = blockIdx.x / nchunk;
  int c4 = threadIdx.x;                       // float4 column, covers all 1024 c
  const float4* xp = (const float4*)(X + ((size_t)b * NN + (size_t)nc * NC) * DIM) + c4;
  const float*  wp = w + ((size_t)b * NN + (size_t)nc * NC) * HEADS;
  float4 acc[HEADS];
  #pragma unroll
  for (int h = 0; h < HEADS; ++h) acc[h] = make_float4(0.f, 0.f, 0.f, 0.f);
  #pragma unroll 2
  for (int n = 0; n < NC; ++n) {
    float4 x4 = xp[(size_t)n * 256];
    const float4* wn = (const float4*)(wp + n * HEADS);  // uniform across wave
    float4 w0 = wn[0], w1 = wn[1], w2 = wn[2], w3 = wn[3];
    fma4(acc[0],  w0.x, x4); fma4(acc[1],  w0.y, x4);
    fma4(acc[2],  w0.z, x4); fma4(acc[3],  w0.w, x4);
    fma4(acc[4],  w1.x, x4); fma4(acc[5],  w1.y, x4);
    fma4(acc[6],  w1.z, x4); fma4(acc[7],  w1.w, x4);
    fma4(acc[8],  w2.x, x4); fma4(acc[9],  w2.y, x4);
    fma4(acc[10], w2.z, x4); fma4(acc[11], w2.w, x4);
    fma4(acc[12], w3.x, x4); fma4(acc[13], w3.y, x4);
    fma4(acc[14], w3.z, x4); fma4(acc[15], w3.w, x4);
  }
  float* zp = Zp + ((size_t)(nc * BB + b)) * HEADS * DIM + c4 * 4;
  #pragma unroll
  for (int h = 0; h < HEADS; ++h) *(float4*)(zp + (size_t)h * DIM) = acc[h];
}

// ---------------- K5b: reduce partials (float4) ----------------
__global__ void k_zred(const float* __restrict__ Zp, float* __restrict__ Z, int nchunk) {
  size_t i = ((size_t)blockIdx.x * 256 + threadIdx.x) * 4;  // grid 512 -> 524288 floats
  const size_t STRIDE = (size_t)BB * HEADS * DIM;
  float4 s = *(const float4*)(Zp + i);
  for (int c = 1; c < nchunk; ++c) {
    float4 p = *(const float4*)(Zp + c * STRIDE + i);
    s.x += p.x; s.y += p.y; s.z += p.z; s.w += p.w;
  }
  *(float4*)(Z + i) = s;
}

// ---------------- K6: T[b,df] = Z[b,h(df),:] . Wv[df,:] ----------------
__global__ void k_ov(const float* __restrict__ Z, const float* __restrict__ Wv,
                     float* __restrict__ T) {
  int wave = threadIdx.x >> 6, lane = threadIdx.x & 63;
  int dfb = blockIdx.x;                       // grid 256
  for (int dot = wave; dot < 128; dot += 4) {
    int b = dot >> 2, dfl = dot & 3;
    int df = dfb * 4 + dfl, h = df >> 6;
    const float* wr = Wv + (size_t)df * DIM + lane * 4;
    const float* zr = Z + ((size_t)b * HEADS + h) * DIM + lane * 4;
    float acc = 0.f;
    #pragma unroll
    for (int k = 0; k < 4; ++k) {
      float4 a = *(const float4*)(wr + k * 256);
      float4 z = *(const float4*)(zr + k * 256);
      acc += a.x * z.x + a.y * z.y + a.z * z.z + a.w * z.w;
    }
    #pragma unroll
    for (int off = 32; off; off >>= 1) acc += __shfl_xor(acc, off);
    if (lane == 0) T[(size_t)b * DIM + df] = acc;
  }
}

// ---------------- K7: U = LN0(S + T + l*bv) ----------------
__global__ void k_ln0(const float* __restrict__ S, const float* __restrict__ T,
                      const float* __restrict__ lsum, const float* __restrict__ bv,
                      const float* __restrict__ g0, const float* __restrict__ b0,
                      float* __restrict__ U) {
  __shared__ float red[4];
  int b = blockIdx.x, tid = threadIdx.x, d0 = tid * 4;   // grid 32
  float4 s4 = *(const float4*)(S + d0);
  float4 t4 = *(const float4*)(T + (size_t)b * DIM + d0);
  float4 v4 = *(const float4*)(bv + d0);
  float lh = lsum[b * HEADS + (d0 >> 6)];
  float x0 = s4.x + t4.x + lh * v4.x;
  float x1 = s4.y + t4.y + lh * v4.y;
  float x2 = s4.z + t4.z + lh * v4.z;
  float x3 = s4.w + t4.w + lh * v4.w;
  float mu = block_sum256(x0 + x1 + x2 + x3, red) * (1.f / DIM);
  float e0 = x0 - mu, e1 = x1 - mu, e2 = x2 - mu, e3 = x3 - mu;
  float var = block_sum256(e0 * e0 + e1 * e1 + e2 * e2 + e3 * e3, red) * (1.f / DIM);
  float r = rsqrtf(var + LN_EPS);
  float4 g4 = *(const float4*)(g0 + d0);
  float4 bb4 = *(const float4*)(b0 + d0);
  float4 o;
  o.x = e0 * r * g4.x + bb4.x;
  o.y = e1 * r * g4.y + bb4.y;
  o.z = e2 * r * g4.z + bb4.z;
  o.w = e3 * r * g4.w + bb4.w;
  *(float4*)(U + (size_t)b * DIM + d0) = o;
}

// ---------------- K8: R = relu(U . Wo^T + bo) ----------------
__global__ void k_wo(const float* __restrict__ U, const float* __restrict__ Wo,
                     const float* __restrict__ bo, float* __restrict__ R) {
  int wave = threadIdx.x >> 6, lane = threadIdx.x & 63;
  int dfb = blockIdx.x;                       // grid 256
  for (int dot = wave; dot < 128; dot += 4) {
    int b = dot >> 2, dfl = dot & 3;
    int df = dfb * 4 + dfl;
    const float* wr = Wo + (size_t)df * DIM + lane * 4;
    const float* ur = U + (size_t)b * DIM + lane * 4;
    float acc = 0.f;
    #pragma unroll
    for (int k = 0; k < 4; ++k) {
      float4 a = *(const float4*)(wr + k * 256);
      float4 u = *(const float4*)(ur + k * 256);
      acc += a.x * u.x + a.y * u.y + a.z * u.z + a.w * u.w;
    }
    #pragma unroll
    for (int off = 32; off; off >>= 1) acc += __shfl_xor(acc, off);
    if (lane == 0) R[(size_t)b * DIM + df] = fmaxf(acc + bo[df], 0.f);
  }
}

// ---------------- K9: out = LN1(U + R) ----------------
__global__ void k_ln1(const float* __restrict__ U, const float* __restrict__ R,
                      const float* __restrict__ g1, const float* __restrict__ b1,
                      float* __restrict__ out) {
  __shared__ float red[4];
  int b = blockIdx.x, tid = threadIdx.x, d0 = tid * 4;   // grid 32
  float4 u4 = *(const float4*)(U + (size_t)b * DIM + d0);
  float4 r4 = *(const float4*)(R + (size_t)b * DIM + d0);
  float x0 = u4.x + r4.x, x1 = u4.y + r4.y, x2 = u4.z + r4.z, x3 = u4.w + r4.w;
  float mu = block_sum256(x0 + x1 + x2 + x3, red) * (1.f / DIM);
  float e0 = x0 - mu, e1 = x1 - mu, e2 = x2 - mu, e3 = x3 - mu;
  float var = block_sum256(e0 * e0 + e1 * e1 + e2 * e2 + e3 * e3, red) * (1.f / DIM);
  float r = rsqrtf(var + LN_EPS);
  float4 g4 = *(const float4*)(g1 + d0);
  float4 bb4 = *(const float4*)(b1 + d0);
  float4 o;
  o.x = e0 * r * g4.x + bb4.x;
  o.y = e1 * r * g4.y + bb4.y;
  o.z = e2 * r * g4.z + bb4.z;
  o.w = e3 * r * g4.w + bb4.w;
  *(float4*)(out + (size_t)b * DIM + d0) = o;
}

extern "C" void kernel_launch(void* const* d_in, const int* in_sizes, int n_in,
                              void* d_out, int out_size, void* d_ws, size_t ws_size,
                              hipStream_t stream) {
  (void)in_sizes; (void)n_in; (void)out_size;
  const float* X  = (const float*)d_in[0];
  const int*   mask = (const int*)d_in[1];
  const float* S  = (const float*)d_in[2];
  const float* Wq = (const float*)d_in[3];
  const float* bq = (const float*)d_in[4];
  const float* Wk = (const float*)d_in[5];
  const float* bk = (const float*)d_in[6];
  const float* Wv = (const float*)d_in[7];
  const float* bv = (const float*)d_in[8];
  const float* Wo = (const float*)d_in[9];
  const float* bo = (const float*)d_in[10];
  const float* g0 = (const float*)d_in[11];
  const float* b0 = (const float*)d_in[12];
  const float* g1 = (const float*)d_in[13];
  const float* b1 = (const float*)d_in[14];
  float* out = (float*)d_out;

  // adaptive n-chunking for k_z partials, by available workspace
  const size_t ZSTRIDE = (size_t)BB * HEADS * DIM;        // 524288 floats per chunk
  const size_t BASEF   = 1048576 + 524288 + 1024 + 16384 + 16 + 512 + 1024; // w+Z+small+pad
  int nchunk = 16;
  if (ws_size < (BASEF + 16 * ZSTRIDE) * 4) nchunk = 8;
  if (ws_size < (BASEF + 8  * ZSTRIDE) * 4) nchunk = 4;
  int NC = NN / nchunk;

  float* W    = (float*)d_ws;
  float* Zp   = W;                            // nchunk * 524288 f
  float* P    = W;                            // alias: 1,048,576 f (dead before k_z2)
  float* w    = W + (size_t)nchunk * ZSTRIDE; // 1,048,576 f, [b][n][h]
  float* Z    = w + 1048576;                  //   524,288 f
  float* Qp   = Z + 524288;
  float* qk   = Qp + 1024;
  float* qb   = qk + 16384;
  float* lsum = qb + 16;
  float* T    = w;                            // alias: w dead after k_z2
  float* U    = w + 32768;
  float* R    = w + 65536;

  k_qp      <<<64,            256, 0, stream>>>(S, Wq, bq, Qp);
  k_qk      <<<64,            256, 0, stream>>>(Qp, Wk, bk, qk, qb);
  k_scores3 <<<512,           256, 0, stream>>>(X, qk, P);
  k_softmax2<<<512,           256, 0, stream>>>(mask, P, qb, w, lsum);
  k_z2      <<<32 * nchunk,   256, 0, stream>>>(X, w, Zp, nchunk, NC);
  k_zred    <<<512,           256, 0, stream>>>(Zp, Z, nchunk);
  k_ov      <<<256,           256, 0, stream>>>(Z, Wv, T);
  k_ln0     <<<32,            256, 0, stream>>>(S, T, lsum, bv, g0, b0, U);
  k_wo      <<<256,           256, 0, stream>>>(U, Wo, bo, R);
  k_ln1     <<<32,            256, 0, stream>>>(U, R, g1, b1, out);
}

// Round 4
// 144.414 us; speedup vs baseline: 2.3367x; 1.3706x over previous
//
#include <hip/hip_runtime.h>
#include <hip/hip_bf16.h>
#include <cstdint>

#define DIM   1024
#define HEADS 16
#define BB    32
#define NN    2048
#define DH    64

constexpr float SCALE = 0.03125f;  // 1/sqrt(1024)
constexpr float LN_EPS = 1e-5f;

typedef __attribute__((ext_vector_type(8))) short short8v;
typedef __attribute__((ext_vector_type(4))) float f32x4;

__device__ __forceinline__ short f2bf(float f) {
  union { __hip_bfloat16 h; short s; } u;
  u.h = __float2bfloat16(f);
  return u.s;
}
__device__ __forceinline__ short8v pack8(float4 a, float4 b) {
  short8v v;
  v[0] = f2bf(a.x); v[1] = f2bf(a.y); v[2] = f2bf(a.z); v[3] = f2bf(a.w);
  v[4] = f2bf(b.x); v[5] = f2bf(b.y); v[6] = f2bf(b.z); v[7] = f2bf(b.w);
  return v;
}
__device__ __forceinline__ void fma4(float4& a, float s, float4 x) {
  a.x += s * x.x; a.y += s * x.y; a.z += s * x.z; a.w += s * x.w;
}

// ---------------- helpers ----------------
__device__ __forceinline__ float block_sum256(float v, volatile float* red) {
  #pragma unroll
  for (int off = 32; off; off >>= 1) v += __shfl_xor(v, off);
  __syncthreads();
  if ((threadIdx.x & 63) == 0) red[threadIdx.x >> 6] = v;
  __syncthreads();
  return red[0] + red[1] + red[2] + red[3];
}

// ---------------- K0: compact unmasked indices per batch ----------------
__global__ void k_index(const int* __restrict__ mask, int* __restrict__ idx,
                        int* __restrict__ cnt) {
  int b = blockIdx.x;                          // grid 32
  int tid = threadIdx.x;
  const int* mb = mask + b * NN;
  int base = tid * 8;
  int loc[8], c = 0;
  #pragma unroll
  for (int i = 0; i < 8; ++i) { loc[i] = mb[base + i]; c += (loc[i] != 0); }
  int pre = c;
  #pragma unroll
  for (int off = 1; off < 64; off <<= 1) {
    int y = __shfl_up(pre, off);
    if ((tid & 63) >= off) pre += y;
  }
  __shared__ int wsum[4];
  if ((tid & 63) == 63) wsum[tid >> 6] = pre;
  __syncthreads();
  int wo = 0;
  for (int wv = 0; wv < (tid >> 6); ++wv) wo += wsum[wv];
  int pos = wo + pre - c;                      // exclusive prefix
  int* ib = idx + b * NN;
  #pragma unroll
  for (int i = 0; i < 8; ++i) if (loc[i]) ib[pos++] = base + i;
  if (tid == 255) cnt[b] = wo + pre;
}

// ---------------- K1: Qp[d] = S . Wq[d,:] + bq[d] ----------------
__global__ void k_qp(const float* __restrict__ S, const float* __restrict__ Wq,
                     const float* __restrict__ bq, float* __restrict__ Qp) {
  int wave = threadIdx.x >> 6, lane = threadIdx.x & 63;
  int d0 = blockIdx.x * 16 + wave * 4;        // grid 64
  #pragma unroll
  for (int i = 0; i < 4; ++i) {
    int d = d0 + i;
    const float* wr = Wq + (size_t)d * DIM;
    float acc = 0.f;
    #pragma unroll
    for (int k = 0; k < 4; ++k) {
      int c = k * 256 + lane * 4;
      float4 a = *(const float4*)(wr + c);
      float4 s = *(const float4*)(S + c);
      acc += a.x * s.x + a.y * s.y + a.z * s.z + a.w * s.w;
    }
    #pragma unroll
    for (int off = 32; off; off >>= 1) acc += __shfl_xor(acc, off);
    if (lane == 0) Qp[d] = acc + bq[d];
  }
}

// ---------------- K2: qk[h,c] = sum_d Qp[h*64+d]*Wk[h*64+d,c]; qb[h] ----------------
__global__ void k_qk(const float* __restrict__ Qp, const float* __restrict__ Wk,
                     const float* __restrict__ bk, float* __restrict__ qk,
                     float* __restrict__ qb) {
  int i = blockIdx.x * 256 + threadIdx.x;     // grid 64 -> 16384
  int h = i >> 10, c = i & 1023;
  const float* qph = Qp + h * DH;
  float acc = 0.f;
  #pragma unroll 8
  for (int d = 0; d < DH; ++d) acc += qph[d] * Wk[(size_t)(h * DH + d) * DIM + c];
  qk[i] = acc;
  if (i < HEADS) {
    float a = 0.f;
    for (int d = 0; d < DH; ++d) a += Qp[i * DH + d] * bk[i * DH + d];
    qb[i] = a;
  }
}

// ---------------- K3 v4: MFMA scores over COMPACT rows ----------------
// grid 256 = 32 b x 8 tilegroups; block loops tiles of 128 compact slots.
// P[b][slot][h] = X[idx[b][slot],:] . qk[h,:]
__global__ __launch_bounds__(256) void k_scores4(const float* __restrict__ X,
                                                 const float* __restrict__ qk,
                                                 const int* __restrict__ idx,
                                                 const int* __restrict__ cnt,
                                                 float* __restrict__ P) {
  int b  = blockIdx.x >> 3;
  int tg = blockIdx.x & 7;
  int count = cnt[b];
  int ntiles = (count + 127) >> 7;
  if (ntiles == 0) return;
  __shared__ short qlds[HEADS * 1024];        // 32 KB bf16, XOR-swizzled slots
  int tid = threadIdx.x;
  for (int i = tid; i < HEADS * 128; i += 256) {
    int h = i >> 7, slot = i & 127;
    const float4* qg = (const float4*)(qk + (size_t)h * DIM) + slot * 2;
    float4 f0 = qg[0], f1 = qg[1];
    int ds = slot ^ (h & 7);
    *(short8v*)(qlds + h * 1024 + ds * 8) = pack8(f0, f1);
  }
  __syncthreads();
  int wv = tid >> 6, lane = tid & 63;
  int r16 = lane & 15, kg = lane >> 4;
  const short* qrow = qlds + r16 * 1024;
  int hx = r16 & 7;
  const int* ib = idx + b * NN;

  for (int t = tg; t < ntiles; t += 8) {
    int tilebase = t * 128 + wv * 32;
    int s0 = tilebase + r16, s1 = s0 + 16;
    int c0 = s0 < count ? s0 : count - 1;
    int c1 = s1 < count ? s1 : count - 1;
    int i0 = ib[c0], i1 = ib[c1];
    const float* x0 = X + ((size_t)b * NN + i0) * DIM + kg * 8;
    const float* x1 = X + ((size_t)b * NN + i1) * DIM + kg * 8;
    f32x4 acc0 = {0.f, 0.f, 0.f, 0.f}, acc1 = {0.f, 0.f, 0.f, 0.f};
    #pragma unroll 4
    for (int k0 = 0; k0 < DIM; k0 += 32) {
      float4 a00 = *(const float4*)(x0 + k0);
      float4 a01 = *(const float4*)(x0 + k0 + 4);
      float4 a10 = *(const float4*)(x1 + k0);
      float4 a11 = *(const float4*)(x1 + k0 + 4);
      short8v bfr = *(const short8v*)(qrow + ((((k0 >> 3) + kg) ^ hx) << 3));
      short8v af0 = pack8(a00, a01);
      short8v af1 = pack8(a10, a11);
      acc0 = __builtin_amdgcn_mfma_f32_16x16x32_bf16(af0, bfr, acc0, 0, 0, 0);
      acc1 = __builtin_amdgcn_mfma_f32_16x16x32_bf16(af1, bfr, acc1, 0, 0, 0);
    }
    // C/D: col(lane&15)=h-ish? no: col=r16 is h; row = kg*4+j is slot-within-16
    float* pb = P + (size_t)b * NN * HEADS + r16;
    #pragma unroll
    for (int j = 0; j < 4; ++j) {
      int os = tilebase + kg * 4 + j;
      if (os < count) pb[(size_t)os * HEADS] = acc0[j];
    }
    #pragma unroll
    for (int j = 0; j < 4; ++j) {
      int os = tilebase + 16 + kg * 4 + j;
      if (os < count) pb[(size_t)os * HEADS] = acc1[j];
    }
  }
}

// ---------------- K4: bias + scale + softmax over compact slots; w [b][slot][h] ----------------
__global__ void k_softmax3(const float* __restrict__ P, const float* __restrict__ qb,
                           const int* __restrict__ cnt, float* __restrict__ w,
                           float* __restrict__ lsum) {
  int b = blockIdx.x >> 4, h = blockIdx.x & 15;   // grid 512
  int tid = threadIdx.x;
  int count = cnt[b];
  const float* p0 = P + ((size_t)b * NN) * HEADS + h;
  float qbh = qb[h];
  __shared__ float red[4];
  float s[8]; int vld[8];
  float mx = -3e38f;
  #pragma unroll
  for (int i = 0; i < 8; ++i) {
    int n = tid + i * 256;
    vld[i] = n < count;
    s[i] = vld[i] ? (p0[(size_t)n * HEADS] + qbh) * SCALE : 0.f;
    if (vld[i]) mx = fmaxf(mx, s[i]);
  }
  #pragma unroll
  for (int off = 32; off; off >>= 1) mx = fmaxf(mx, __shfl_xor(mx, off));
  if ((tid & 63) == 0) red[tid >> 6] = mx;
  __syncthreads();
  mx = fmaxf(fmaxf(red[0], red[1]), fmaxf(red[2], red[3]));
  float sum = 0.f;
  #pragma unroll
  for (int i = 0; i < 8; ++i) {
    float e = vld[i] ? __expf(s[i] - mx) : 0.f;
    s[i] = e;
    sum += e;
  }
  #pragma unroll
  for (int off = 32; off; off >>= 1) sum += __shfl_xor(sum, off);
  __syncthreads();
  if ((tid & 63) == 0) red[tid >> 6] = sum;
  __syncthreads();
  sum = red[0] + red[1] + red[2] + red[3];
  float inv = sum > 0.f ? 1.f / sum : 0.f;
  float* wb = w + (size_t)b * NN * HEADS + h;
  #pragma unroll
  for (int i = 0; i < 8; ++i) {
    int n = tid + i * 256;
    if (vld[i]) wb[(size_t)n * HEADS] = s[i] * inv;
  }
  if (tid == 0) lsum[b * HEADS + h] = sum > 0.f ? 1.f : 0.f;
}

// ---------------- K5 v3: Z partials over compact rows ----------------
__global__ __launch_bounds__(256) void k_z3(const float* __restrict__ X,
                                            const float* __restrict__ w,
                                            const int* __restrict__ idx,
                                            const int* __restrict__ cnt,
                                            float* __restrict__ Zp, int nchunk) {
  int nc = blockIdx.x % nchunk;
  int b  = blockIdx.x / nchunk;
  int count = cnt[b];
  int NCc = (count + nchunk - 1) / nchunk;
  int start = nc * NCc;
  int end = start + NCc; if (end > count) end = count;
  int c4 = threadIdx.x;
  const float* Xb = X + (size_t)b * NN * DIM;
  const float* wp = w + ((size_t)b * NN) * HEADS;
  const int* ib = idx + b * NN;
  float4 acc[HEADS];
  #pragma unroll
  for (int h = 0; h < HEADS; ++h) acc[h] = make_float4(0.f, 0.f, 0.f, 0.f);
  #pragma unroll 2
  for (int slot = start; slot < end; ++slot) {
    int n = ib[slot];
    float4 x4 = *(const float4*)(Xb + (size_t)n * DIM + c4 * 4);
    const float4* wn = (const float4*)(wp + (size_t)slot * HEADS);  // uniform
    float4 w0 = wn[0], w1 = wn[1], w2 = wn[2], w3 = wn[3];
    fma4(acc[0],  w0.x, x4); fma4(acc[1],  w0.y, x4);
    fma4(acc[2],  w0.z, x4); fma4(acc[3],  w0.w, x4);
    fma4(acc[4],  w1.x, x4); fma4(acc[5],  w1.y, x4);
    fma4(acc[6],  w1.z, x4); fma4(acc[7],  w1.w, x4);
    fma4(acc[8],  w2.x, x4); fma4(acc[9],  w2.y, x4);
    fma4(acc[10], w2.z, x4); fma4(acc[11], w2.w, x4);
    fma4(acc[12], w3.x, x4); fma4(acc[13], w3.y, x4);
    fma4(acc[14], w3.z, x4); fma4(acc[15], w3.w, x4);
  }
  float* zp = Zp + ((size_t)(nc * BB + b)) * HEADS * DIM + c4 * 4;
  #pragma unroll
  for (int h = 0; h < HEADS; ++h) *(float4*)(zp + (size_t)h * DIM) = acc[h];
}

// ---------------- K5b: reduce partials (float4) ----------------
__global__ void k_zred(const float* __restrict__ Zp, float* __restrict__ Z, int nchunk) {
  size_t i = ((size_t)blockIdx.x * 256 + threadIdx.x) * 4;  // grid 512 -> 524288 floats
  const size_t STRIDE = (size_t)BB * HEADS * DIM;
  float4 s = *(const float4*)(Zp + i);
  for (int c = 1; c < nchunk; ++c) {
    float4 p = *(const float4*)(Zp + c * STRIDE + i);
    s.x += p.x; s.y += p.y; s.z += p.z; s.w += p.w;
  }
  *(float4*)(Z + i) = s;
}

// ---------------- K6: T[b,df] = Z[b,h(df),:] . Wv[df,:] ----------------
__global__ void k_ov(const float* __restrict__ Z, const float* __restrict__ Wv,
                     float* __restrict__ T) {
  int wave = threadIdx.x >> 6, lane = threadIdx.x & 63;
  int dfb = blockIdx.x;                       // grid 256
  for (int dot = wave; dot < 128; dot += 4) {
    int b = dot >> 2, dfl = dot & 3;
    int df = dfb * 4 + dfl, h = df >> 6;
    const float* wr = Wv + (size_t)df * DIM + lane * 4;
    const float* zr = Z + ((size_t)b * HEADS + h) * DIM + lane * 4;
    float acc = 0.f;
    #pragma unroll
    for (int k = 0; k < 4; ++k) {
      float4 a = *(const float4*)(wr + k * 256);
      float4 z = *(const float4*)(zr + k * 256);
      acc += a.x * z.x + a.y * z.y + a.z * z.z + a.w * z.w;
    }
    #pragma unroll
    for (int off = 32; off; off >>= 1) acc += __shfl_xor(acc, off);
    if (lane == 0) T[(size_t)b * DIM + df] = acc;
  }
}

// ---------------- K7: U = LN0(S + T + l*bv) ----------------
__global__ void k_ln0(const float* __restrict__ S, const float* __restrict__ T,
                      const float* __restrict__ lsum, const float* __restrict__ bv,
                      const float* __restrict__ g0, const float* __restrict__ b0,
                      float* __restrict__ U) {
  __shared__ float red[4];
  int b = blockIdx.x, tid = threadIdx.x, d0 = tid * 4;   // grid 32
  float4 s4 = *(const float4*)(S + d0);
  float4 t4 = *(const float4*)(T + (size_t)b * DIM + d0);
  float4 v4 = *(const float4*)(bv + d0);
  float lh = lsum[b * HEADS + (d0 >> 6)];
  float x0 = s4.x + t4.x + lh * v4.x;
  float x1 = s4.y + t4.y + lh * v4.y;
  float x2 = s4.z + t4.z + lh * v4.z;
  float x3 = s4.w + t4.w + lh * v4.w;
  float mu = block_sum256(x0 + x1 + x2 + x3, red) * (1.f / DIM);
  float e0 = x0 - mu, e1 = x1 - mu, e2 = x2 - mu, e3 = x3 - mu;
  float var = block_sum256(e0 * e0 + e1 * e1 + e2 * e2 + e3 * e3, red) * (1.f / DIM);
  float r = rsqrtf(var + LN_EPS);
  float4 g4 = *(const float4*)(g0 + d0);
  float4 bb4 = *(const float4*)(b0 + d0);
  float4 o;
  o.x = e0 * r * g4.x + bb4.x;
  o.y = e1 * r * g4.y + bb4.y;
  o.z = e2 * r * g4.z + bb4.z;
  o.w = e3 * r * g4.w + bb4.w;
  *(float4*)(U + (size_t)b * DIM + d0) = o;
}

// ---------------- K8: R = relu(U . Wo^T + bo) ----------------
__global__ void k_wo(const float* __restrict__ U, const float* __restrict__ Wo,
                     const float* __restrict__ bo, float* __restrict__ R) {
  int wave = threadIdx.x >> 6, lane = threadIdx.x & 63;
  int dfb = blockIdx.x;                       // grid 256
  for (int dot = wave; dot < 128; dot += 4) {
    int b = dot >> 2, dfl = dot & 3;
    int df = dfb * 4 + dfl;
    const float* wr = Wo + (size_t)df * DIM + lane * 4;
    const float* ur = U + (size_t)b * DIM + lane * 4;
    float acc = 0.f;
    #pragma unroll
    for (int k = 0; k < 4; ++k) {
      float4 a = *(const float4*)(wr + k * 256);
      float4 u = *(const float4*)(ur + k * 256);
      acc += a.x * u.x + a.y * u.y + a.z * u.z + a.w * u.w;
    }
    #pragma unroll
    for (int off = 32; off; off >>= 1) acc += __shfl_xor(acc, off);
    if (lane == 0) R[(size_t)b * DIM + df] = fmaxf(acc + bo[df], 0.f);
  }
}

// ---------------- K9: out = LN1(U + R) ----------------
__global__ void k_ln1(const float* __restrict__ U, const float* __restrict__ R,
                      const float* __restrict__ g1, const float* __restrict__ b1,
                      float* __restrict__ out) {
  __shared__ float red[4];
  int b = blockIdx.x, tid = threadIdx.x, d0 = tid * 4;   // grid 32
  float4 u4 = *(const float4*)(U + (size_t)b * DIM + d0);
  float4 r4 = *(const float4*)(R + (size_t)b * DIM + d0);
  float x0 = u4.x + r4.x, x1 = u4.y + r4.y, x2 = u4.z + r4.z, x3 = u4.w + r4.w;
  float mu = block_sum256(x0 + x1 + x2 + x3, red) * (1.f / DIM);
  float e0 = x0 - mu, e1 = x1 - mu, e2 = x2 - mu, e3 = x3 - mu;
  float var = block_sum256(e0 * e0 + e1 * e1 + e2 * e2 + e3 * e3, red) * (1.f / DIM);
  float r = rsqrtf(var + LN_EPS);
  float4 g4 = *(const float4*)(g1 + d0);
  float4 bb4 = *(const float4*)(b1 + d0);
  float4 o;
  o.x = e0 * r * g4.x + bb4.x;
  o.y = e1 * r * g4.y + bb4.y;
  o.z = e2 * r * g4.z + bb4.z;
  o.w = e3 * r * g4.w + bb4.w;
  *(float4*)(out + (size_t)b * DIM + d0) = o;
}

extern "C" void kernel_launch(void* const* d_in, const int* in_sizes, int n_in,
                              void* d_out, int out_size, void* d_ws, size_t ws_size,
                              hipStream_t stream) {
  (void)in_sizes; (void)n_in; (void)out_size;
  const float* X  = (const float*)d_in[0];
  const int*   mask = (const int*)d_in[1];
  const float* S  = (const float*)d_in[2];
  const float* Wq = (const float*)d_in[3];
  const float* bq = (const float*)d_in[4];
  const float* Wk = (const float*)d_in[5];
  const float* bk = (const float*)d_in[6];
  const float* Wv = (const float*)d_in[7];
  const float* bv = (const float*)d_in[8];
  const float* Wo = (const float*)d_in[9];
  const float* bo = (const float*)d_in[10];
  const float* g0 = (const float*)d_in[11];
  const float* b0 = (const float*)d_in[12];
  const float* g1 = (const float*)d_in[13];
  const float* b1 = (const float*)d_in[14];
  float* out = (float*)d_out;

  const size_t ZSTRIDE = (size_t)BB * HEADS * DIM;        // 524288 floats per chunk
  const size_t BASEF   = 1048576 + 524288 + 1024 + 16384 + 16 + 512 + 65536 + 64 + 1024;
  int nchunk = 16;
  if (ws_size < (BASEF + 16 * ZSTRIDE) * 4) nchunk = 8;
  if (ws_size < (BASEF + 8  * ZSTRIDE) * 4) nchunk = 4;

  float* W    = (float*)d_ws;
  float* Zp   = W;                            // nchunk * 524288 f
  float* P    = W;                            // alias: 1,048,576 f (dead before k_z3)
  float* w    = W + (size_t)nchunk * ZSTRIDE; // 1,048,576 f, [b][slot][h]
  float* Z    = w + 1048576;                  //   524,288 f
  float* Qp   = Z + 524288;
  float* qk   = Qp + 1024;
  float* qb   = qk + 16384;
  float* lsum = qb + 16;
  int*   idx  = (int*)(lsum + 512);           // 65,536 ints
  int*   cnt  = idx + 65536;                  // 32 ints
  float* T    = w;                            // alias: w dead after k_z3
  float* U    = w + 32768;
  float* R    = w + 65536;

  k_index   <<<32,            256, 0, stream>>>(mask, idx, cnt);
  k_qp      <<<64,            256, 0, stream>>>(S, Wq, bq, Qp);
  k_qk      <<<64,            256, 0, stream>>>(Qp, Wk, bk, qk, qb);
  k_scores4 <<<256,           256, 0, stream>>>(X, qk, idx, cnt, P);
  k_softmax3<<<512,           256, 0, stream>>>(P, qb, cnt, w, lsum);
  k_z3      <<<32 * nchunk,   256, 0, stream>>>(X, w, idx, cnt, Zp, nchunk);
  k_zred    <<<512,           256, 0, stream>>>(Zp, Z, nchunk);
  k_ov      <<<256,           256, 0, stream>>>(Z, Wv, T);
  k_ln0     <<<32,            256, 0, stream>>>(S, T, lsum, bv, g0, b0, U);
  k_wo      <<<256,           256, 0, stream>>>(U, Wo, bo, R);
  k_ln1     <<<32,            256, 0, stream>>>(U, R, g1, b1, out);
}